// Round 1
// baseline (118.816 us; speedup 1.0000x reference)
//
#include <hip/hip_runtime.h>
#include <math.h>

#define NQ 8
#define DIM 256
#define NW 26

// One wave (64 lanes) per batch element; lane L holds amplitudes 4L..4L+3.
// Wire w <-> state-index bit (7-w). Wires 6,7 = in-lane bits; wires 0..5 =
// lane bits 5..0 (shfl_xor butterflies). State stays exactly real; Y evs = 0.
__global__ __launch_bounds__(256) void qae_kernel(const float* __restrict__ x,
                                                  const float* __restrict__ w,
                                                  float* __restrict__ out,
                                                  int batch) {
    const int lane = threadIdx.x & 63;
    const int wavesPerBlock = blockDim.x >> 6;
    const int wave = blockIdx.x * wavesPerBlock + (threadIdx.x >> 6);
    const int nwaves = gridDim.x * wavesPerBlock;

    // cos/sin of each weight/2 (wave-uniform, kept in registers)
    float cc[NW], sn[NW];
#pragma unroll
    for (int g = 0; g < NW; ++g) {
        float h = 0.5f * w[g];
        cc[g] = cosf(h);
        sn[g] = sinf(h);
    }

    // Fused CZ-layer sign for this lane's 4 amplitudes:
    // exponent = b0*b1 + (b0+b1) * sum(bits of wires 2..7)
    // wire0 bit = lane bit5, wire1 bit = lane bit4,
    // wires2..7 bits = (lane bits 3..0, k bits 1..0)
    float cz[4];
    {
        const int b0 = (lane >> 5) & 1;
        const int b1 = (lane >> 4) & 1;
        const int basepop = __popc(lane & 15);
#pragma unroll
        for (int k = 0; k < 4; ++k) {
            int e = b0 * b1 + (b0 + b1) * (basepop + __popc(k));
            cz[k] = (e & 1) ? -1.0f : 1.0f;
        }
    }

    for (int b = wave; b < batch; b += nwaves) {
        const float4 v4 = *(const float4*)(x + (size_t)b * DIM + lane * 4);
        float v0 = v4.x, v1 = v4.y, v2 = v4.z, v3 = v4.w;
        // norm^2 partial (RY/CZ preserve the norm; divide at the end)
        float nrm2 = v0 * v0 + v1 * v1 + v2 * v2 + v3 * v3;

#pragma unroll
        for (int l = 0; l < 3; ++l) {
            // wires 0..5: cross-lane butterflies
#pragma unroll
            for (int q = 0; q < 6; ++q) {
                const float c = cc[l * 8 + q], s = sn[l * 8 + q];
                const int mask = 1 << (5 - q);
                // wire-bit 0 lanes: new = c*own - s*other; bit 1: c*own + s*other
                const float sg = ((lane >> (5 - q)) & 1) ? s : -s;
                float o0 = __shfl_xor(v0, mask);
                float o1 = __shfl_xor(v1, mask);
                float o2 = __shfl_xor(v2, mask);
                float o3 = __shfl_xor(v3, mask);
                v0 = fmaf(sg, o0, c * v0);
                v1 = fmaf(sg, o1, c * v1);
                v2 = fmaf(sg, o2, c * v2);
                v3 = fmaf(sg, o3, c * v3);
            }
            // wire 6 (k bit1): pairs (v0,v2),(v1,v3)
            {
                const float c = cc[l * 8 + 6], s = sn[l * 8 + 6];
                float n0 = fmaf(-s, v2, c * v0);
                float n2 = fmaf(s, v0, c * v2);
                float n1 = fmaf(-s, v3, c * v1);
                float n3 = fmaf(s, v1, c * v3);
                v0 = n0; v1 = n1; v2 = n2; v3 = n3;
            }
            // wire 7 (k bit0): pairs (v0,v1),(v2,v3)
            {
                const float c = cc[l * 8 + 7], s = sn[l * 8 + 7];
                float n0 = fmaf(-s, v1, c * v0);
                float n1 = fmaf(s, v0, c * v1);
                float n2 = fmaf(-s, v3, c * v2);
                float n3 = fmaf(s, v2, c * v3);
                v0 = n0; v1 = n1; v2 = n2; v3 = n3;
            }
            // fused CZ layer
            v0 *= cz[0]; v1 *= cz[1]; v2 *= cz[2]; v3 *= cz[3];
        }
        // last layer: RY on trash wires 0,1 only
#pragma unroll
        for (int q = 0; q < 2; ++q) {
            const float c = cc[24 + q], s = sn[24 + q];
            const int mask = 1 << (5 - q);
            const float sg = ((lane >> (5 - q)) & 1) ? s : -s;
            float o0 = __shfl_xor(v0, mask);
            float o1 = __shfl_xor(v1, mask);
            float o2 = __shfl_xor(v2, mask);
            float o3 = __shfl_xor(v3, mask);
            v0 = fmaf(sg, o0, c * v0);
            v1 = fmaf(sg, o1, c * v1);
            v2 = fmaf(sg, o2, c * v2);
            v3 = fmaf(sg, o3, c * v3);
        }

        // lane-local expectation partials (ops act on wires 6,7 = in-lane)
        float X6 = 2.f * (v0 * v2 + v1 * v3);
        float X7 = 2.f * (v0 * v1 + v2 * v3);
        float XX = 2.f * (v0 * v3 + v1 * v2);
        float YY = 2.f * (v1 * v2 - v0 * v3);
        float s0 = v0 * v0, s1 = v1 * v1, s2 = v2 * v2, s3 = v3 * v3;
        float Z6 = s0 + s1 - s2 - s3;
        float Z7 = s0 - s1 + s2 - s3;
        float ZZ = s0 - s1 - s2 + s3;

        // butterfly reduce 8 values across the wave
#pragma unroll
        for (int m = 1; m < 64; m <<= 1) {
            nrm2 += __shfl_xor(nrm2, m);
            X6 += __shfl_xor(X6, m);
            X7 += __shfl_xor(X7, m);
            XX += __shfl_xor(XX, m);
            YY += __shfl_xor(YY, m);
            Z6 += __shfl_xor(Z6, m);
            Z7 += __shfl_xor(Z7, m);
            ZZ += __shfl_xor(ZZ, m);
        }

        if (lane == 0) {
            const float inv = 1.0f / nrm2;
            float* o = out + (size_t)b * 9;
            o[0] = X6 * inv;
            o[1] = 0.0f;       // <Y6> == 0 exactly (real state)
            o[2] = Z6 * inv;
            o[3] = X7 * inv;
            o[4] = 0.0f;       // <Y7> == 0 exactly
            o[5] = Z7 * inv;
            o[6] = XX * inv;
            o[7] = YY * inv;
            o[8] = ZZ * inv;
        }
    }
}

extern "C" void kernel_launch(void* const* d_in, const int* in_sizes, int n_in,
                              void* d_out, int out_size, void* d_ws, size_t ws_size,
                              hipStream_t stream) {
    const float* x = (const float*)d_in[0];
    const float* w = (const float*)d_in[1];
    float* out = (float*)d_out;
    const int batch = in_sizes[0] / DIM;

    const int block = 256;               // 4 waves/block
    const int grid = 2048;               // 8192 waves -> 4 elements/wave
    qae_kernel<<<grid, block, 0, stream>>>(x, w, out, batch);
}

// Round 2
// 84.493 us; speedup vs baseline: 1.4062x; 1.4062x over previous
//
#include <hip/hip_runtime.h>
#include <math.h>

#define DIM 256

// ---------------------------------------------------------------------------
// Pre-kernel: cos/sin of each weight/2 into workspace (ws re-poisoned before
// every timed launch, so this must run every kernel_launch).
// ---------------------------------------------------------------------------
__global__ void trig_kernel(const float* __restrict__ w, float* __restrict__ ws) {
    int t = threadIdx.x;
    if (t < 26) {
        float h = 0.5f * w[t];
        ws[t]      = cosf(h);
        ws[26 + t] = sinf(h);
    }
}

// RY on an in-lane wire mapped to bit B of the 32-amp register file.
// pairs (i, i|1<<B): lo' = c*lo - s*hi ; hi' = s*lo + c*hi  (matches [[c,-s],[s,c]])
template<int B>
__device__ __forceinline__ void ry_bit(float* v, float c, float s) {
#pragma unroll
    for (int i = 0; i < 32; ++i) {
        if (!(i & (1 << B))) {
            const int j = i | (1 << B);
            float lo = v[i], hi = v[j];
            v[i] = fmaf(-s, hi, c * lo);
            v[j] = fmaf(s, lo, c * hi);
        }
    }
}

// CZ sign layer in layout A (in-lane bits = wires 3..7):
// parity = (w0&w1) ^ ((w0^w1) & (w2 + popc(i))&1) -> two per-lane factors.
__device__ __forceinline__ void cz_A(float* v, float fE, float fO) {
#pragma unroll
    for (int i = 0; i < 32; ++i) v[i] *= (__popc(i) & 1) ? fO : fE;
}

// CZ sign layer in layout B (in-lane j: bit4=w0, bit3=w1, bit2=w2, bit1=w6, bit0=w7):
// w0=w1=1 -> -1 always; w0^w1 -> +-(lanepop parity); w0=w1=0 -> +1.
__device__ __forceinline__ void cz_B(float* v, float pB, float nB) {
#pragma unroll
    for (int j = 0; j < 32; ++j) {
        const int w0 = (j >> 4) & 1, w1 = (j >> 3) & 1;
        const int ip = __popc(j & 7) & 1;  // w2+w6+w7 parity (compile-time)
        if (w0 & w1)      v[j] = -v[j];
        else if (w0 ^ w1) v[j] *= ip ? nB : pB;
    }
}

// Transpose A->B through the wave-private LDS slice W (64 float4 per element).
// Canonical dword d = w012*32 + w345*4 + w67, XOR-swizzled: float4 index
// p = w012*8 + (w345 ^ w012)  -> every b128 sits at the 8-way data floor.
__device__ __forceinline__ void tA2B(float* v, float4* W, int l3) {
#pragma unroll
    for (int k = 0; k < 8; ++k)   // l3 = w012, k = w345
        W[l3 * 8 + (k ^ l3)] = make_float4(v[4*k], v[4*k+1], v[4*k+2], v[4*k+3]);
#pragma unroll
    for (int g = 0; g < 8; ++g) { // l3 = w345, g = w012
        float4 f = W[g * 8 + (l3 ^ g)];
        v[4*g] = f.x; v[4*g+1] = f.y; v[4*g+2] = f.z; v[4*g+3] = f.w;
    }
}

__device__ __forceinline__ void tB2A(float* v, float4* W, int l3) {
#pragma unroll
    for (int g = 0; g < 8; ++g)   // l3 = w345, g = w012
        W[g * 8 + (l3 ^ g)] = make_float4(v[4*g], v[4*g+1], v[4*g+2], v[4*g+3]);
#pragma unroll
    for (int k = 0; k < 8; ++k) { // l3 = w012, k = w345
        float4 f = W[l3 * 8 + (k ^ l3)];
        v[4*k] = f.x; v[4*k+1] = f.y; v[4*k+2] = f.z; v[4*k+3] = f.w;
    }
}

// One wave = 8 batch elements (8 lanes/element, 32 amps/lane). Every RY gate
// is lane-local; 3 XOR-swizzled LDS transposes swap wires {0,1,2}<->{3,4,5}
// between lane bits and register bits. No __syncthreads (wave-private LDS).
__global__ __launch_bounds__(256) void qae_kernel(const float* __restrict__ x,
                                                  const float* __restrict__ tw,
                                                  float* __restrict__ out,
                                                  int batch) {
    __shared__ float4 lds4[2048];            // 4 waves * 8 elem * 64 float4
    const int lane = threadIdx.x & 63;
    const int wave = blockIdx.x * 4 + (threadIdx.x >> 6);
    const int l3   = lane & 7;               // w012 in layout A, w345 in layout B
    const int e    = lane >> 3;              // element slot within the wave
    const int eb   = wave * 8 + e;           // batch element
    float4* W = lds4 + (threadIdx.x >> 6) * 512 + e * 64;

    const float* CW = tw;                    // cos(theta/2), wave-uniform scalar loads
    const float* SW = tw + 26;

    // per-lane CZ factors
    const int a_w0 = (l3 >> 2) & 1, a_w1 = (l3 >> 1) & 1, a_w2 = l3 & 1;
    const int aa = a_w0 & a_w1, dd = a_w0 ^ a_w1;
    const float fE = (aa ^ (dd & a_w2)) ? -1.f : 1.f;
    const float fO = ((aa ^ (dd & a_w2)) ^ dd) ? -1.f : 1.f;
    const float pB = (__popc(l3) & 1) ? -1.f : 1.f;
    const float nB = -pB;

    // load in layout A: v[i], i bits = w3..w7 (bit4=w3 .. bit0=w7), contiguous in x
    float v[32];
    if (eb < batch) {
        const float* xp = x + (size_t)eb * DIM + l3 * 32;
#pragma unroll
        for (int k = 0; k < 8; ++k) {
            float4 f = *(const float4*)(xp + 4 * k);
            v[4*k] = f.x; v[4*k+1] = f.y; v[4*k+2] = f.z; v[4*k+3] = f.w;
        }
    } else {
#pragma unroll
        for (int i = 0; i < 32; ++i) v[i] = 0.f;
    }
    float nrm2 = 0.f;
#pragma unroll
    for (int i = 0; i < 32; ++i) nrm2 = fmaf(v[i], v[i], nrm2);

#define RY(b, g) ry_bit<b>(v, CW[g], SW[g])
    // ---- layer 0, wires 3..7 (A: wire q -> bit 7-q)
    RY(4, 3); RY(3, 4); RY(2, 5); RY(1, 6); RY(0, 7);
    tA2B(v, W, l3);
    // ---- B: layer 0 wires 0,1,2 (bit4=w0,bit3=w1,bit2=w2); CZ0; layer 1 wires 0,1,2
    RY(4, 0); RY(3, 1); RY(2, 2);
    cz_B(v, pB, nB);
    RY(4, 8); RY(3, 9); RY(2, 10);
    tB2A(v, W, l3);
    // ---- A: layer 1 wires 3..7; CZ1; layer 2 wires 3..7
    RY(4, 11); RY(3, 12); RY(2, 13); RY(1, 14); RY(0, 15);
    cz_A(v, fE, fO);
    RY(4, 19); RY(3, 20); RY(2, 21); RY(1, 22); RY(0, 23);
    tA2B(v, W, l3);
    // ---- B: layer 2 wires 0,1,2; CZ2; final RY on trash wires 0,1 (weights 24,25)
    RY(4, 16); RY(3, 17); RY(2, 18);
    cz_B(v, pB, nB);
    RY(4, 24); RY(3, 25);
#undef RY

    // epilogue in B: each float4-group g has w67 = {00,01,10,11} (bit1=w6,bit0=w7)
    float X6 = 0, X7 = 0, XX = 0, YY = 0, Z6 = 0, Z7 = 0, ZZ = 0;
#pragma unroll
    for (int g = 0; g < 8; ++g) {
        float q0 = v[4*g], q1 = v[4*g+1], q2 = v[4*g+2], q3 = v[4*g+3];
        X6 += q0*q2 + q1*q3;
        X7 += q0*q1 + q2*q3;
        XX += q0*q3 + q1*q2;
        YY += q1*q2 - q0*q3;
        float s0 = q0*q0, s1 = q1*q1, s2 = q2*q2, s3 = q3*q3;
        Z6 += s0 + s1 - s2 - s3;
        Z7 += s0 - s1 + s2 - s3;
        ZZ += s0 - s1 - s2 + s3;
    }
    X6 *= 2.f; X7 *= 2.f; XX *= 2.f; YY *= 2.f;

    // butterfly over the 8 lanes of this element
#pragma unroll
    for (int m = 1; m < 8; m <<= 1) {
        nrm2 += __shfl_xor(nrm2, m);
        X6 += __shfl_xor(X6, m);  X7 += __shfl_xor(X7, m);
        XX += __shfl_xor(XX, m);  YY += __shfl_xor(YY, m);
        Z6 += __shfl_xor(Z6, m);  Z7 += __shfl_xor(Z7, m);
        ZZ += __shfl_xor(ZZ, m);
    }

    if (eb < batch) {
        const float inv = 1.f / nrm2;   // RY/CZ are orthogonal: norm deferred to here
        float* o = out + (size_t)eb * 9;
        const int t = l3;
        if (t < 7) {
            // out slots: X6->0, Z6->2, X7->3, Z7->5, XX->6, YY->7, ZZ->8
            float val = (t == 0) ? X6 : (t == 1) ? Z6 : (t == 2) ? X7
                      : (t == 3) ? Z7 : (t == 4) ? XX : (t == 5) ? YY : ZZ;
            int off = t + (t >= 1 ? 1 : 0) + (t >= 3 ? 1 : 0);
            o[off] = val * inv;
        } else {
            o[1] = 0.f;   // <Y6> == 0 exactly (state stays real)
            o[4] = 0.f;   // <Y7> == 0 exactly
        }
    }
}

extern "C" void kernel_launch(void* const* d_in, const int* in_sizes, int n_in,
                              void* d_out, int out_size, void* d_ws, size_t ws_size,
                              hipStream_t stream) {
    const float* x = (const float*)d_in[0];
    const float* w = (const float*)d_in[1];
    float* out = (float*)d_out;
    float* ws  = (float*)d_ws;
    const int batch = in_sizes[0] / DIM;

    trig_kernel<<<1, 64, 0, stream>>>(w, ws);

    const int waves  = (batch + 7) / 8;
    const int blocks = (waves + 3) / 4;     // 4 waves / 256-thread block
    qae_kernel<<<blocks, 256, 0, stream>>>(x, ws, out, batch);
}

// Round 3
// 79.623 us; speedup vs baseline: 1.4922x; 1.0612x over previous
//
#include <hip/hip_runtime.h>
#include <math.h>

#define DIM 256
typedef float v2f __attribute__((ext_vector_type(2)));

__device__ __forceinline__ v2f mk2(float a, float b) { v2f r; r.x = a; r.y = b; return r; }

// wave-uniform broadcast lane->SGPR
__device__ __forceinline__ float rl(float v, int l) {
    return __uint_as_float(__builtin_amdgcn_readlane(__float_as_uint(v), l));
}

// RY on v2-index bit B2 (i.e. amp-index bit B2+1): packed float2 update.
// lo' = c*lo - s*hi ; hi' = s*lo + c*hi   (RY = [[c,-s],[s,c]], lo = bit==0)
template<int B2>
__device__ __forceinline__ void ry_pk(v2f* v, float c, float s) {
#pragma unroll
    for (int p = 0; p < 16; ++p)
        if (!(p & (1 << B2))) {
            const int q = p | (1 << B2);
            v2f lo = v[p], hi = v[q];
            v[p] = c * lo - s * hi;
            v[q] = s * lo + c * hi;
        }
}

// RY on amp-index bit 0 (pair inside one float2)
__device__ __forceinline__ void ry_intra(v2f* v, float c, float s) {
#pragma unroll
    for (int p = 0; p < 16; ++p) {
        float lo = v[p].x, hi = v[p].y;
        v[p].x = fmaf(-s, hi, c * lo);
        v[p].y = fmaf(s, lo, c * hi);
    }
}

// One wave = 8 batch elements (8 lanes/elem, 32 amps = 16 float2 per lane).
// Layout B: lane=w3w4w5; in-lane j: bit4=w0,bit3=w1,bit2=w2,bit1=w6,bit0=w7.
// Layout A: lane=w0w1w2; in-lane i: bit4=w3,bit3=w4,bit2=w5,bit1=w6,bit0=w7.
// CZ sign exponent: e = w0*w1 + (w0+w1)*(w2+...+w7)  (all 13 CZs fused).
// Dropped exactly (commute with observables on wires 6,7): weights 24,25 and
// layer-2 RYs on wires 2..5 (weights 18..21).
__global__ __launch_bounds__(256) void qae_kernel(const float* __restrict__ x,
                                                  const float* __restrict__ w,
                                                  float* __restrict__ out,
                                                  int batch) {
    __shared__ float4 lds4[2048];            // 4 waves * 8 elem * 64 float4 = 32 KiB
    const int lane = threadIdx.x & 63;
    const int wave = blockIdx.x * 4 + (threadIdx.x >> 6);
    const int l3   = lane & 7;               // w345 in B, w012 in A
    const int e    = lane >> 3;
    const int eb   = wave * 8 + e;
    float4* W = lds4 + (threadIdx.x >> 6) * 512 + e * 64;

    // ---- in-wave trig: lanes 0..19 hold cos/sin of needed weights ----
    // slots 0..17 -> weights 0..17 ; slot 18 -> weight 22 ; slot 19 -> weight 23
    float h = 0.f;
    if (lane < 20) h = 0.5f * w[lane < 18 ? lane : lane + 4];
    const float cv = __cosf(h), sv = __sinf(h);
#define RYP(B2, slot) ry_pk<B2>(v, rl(cv, slot), rl(sv, slot))
#define RYI(slot)     ry_intra(v, rl(cv, slot), rl(sv, slot))

    // ---- per-lane CZ factors ----
    // layout A (lane = w0w1w2):
    const int a0 = (l3 >> 2) & 1, a1 = (l3 >> 1) & 1, a2 = l3 & 1;
    const int aa = a0 & a1, dd = a0 ^ a1;
    const float fE = (aa ^ (dd & a2)) ? -1.f : 1.f;        // popc(i) even
    const float fO = ((aa ^ (dd & a2)) ^ dd) ? -1.f : 1.f; // popc(i) odd
    // layout B (lane = w3w4w5): parity of lane popcount
    const float pB = (__popc(l3) & 1) ? -1.f : 1.f;
    const v2f mA0 = mk2(fE, fO), mA1 = mk2(fO, fE);
    const v2f mBp = mk2(pB, -pB);            // w0^w1 case, (w7=0, w7=1) halves

    // ---- load directly in layout B (coalesced b128) ----
    v2f v[16];
    if (eb < batch) {
        const float* xp = x + (size_t)eb * DIM + l3 * 4;
#pragma unroll
        for (int u = 0; u < 8; ++u) {        // u = w0w1w2
            float4 f = *(const float4*)(xp + u * 32);
            v[2 * u]     = mk2(f.x, f.y);
            v[2 * u + 1] = mk2(f.z, f.w);
        }
    } else {
#pragma unroll
        for (int p = 0; p < 16; ++p) v[p] = mk2(0.f, 0.f);
    }
    float nrm2 = 0.f;
#pragma unroll
    for (int p = 0; p < 16; ++p) nrm2 += v[p].x * v[p].x + v[p].y * v[p].y;

    // ---- B: layer-0 wires 0,1,2 ----
    RYP(3, 0); RYP(2, 1); RYP(1, 2);

    // ---- transpose B->A (XOR-swizzled, wave-private; 8-way data floor) ----
#pragma unroll
    for (int g = 0; g < 8; ++g)
        W[g * 8 + (l3 ^ g)] = make_float4(v[2*g].x, v[2*g].y, v[2*g+1].x, v[2*g+1].y);
#pragma unroll
    for (int k = 0; k < 8; ++k) {
        float4 f = W[l3 * 8 + (k ^ l3)];
        v[2 * k] = mk2(f.x, f.y); v[2 * k + 1] = mk2(f.z, f.w);
    }

    // ---- A: layer-0 wires 3..7 ; CZ0 ; layer-1 wires 3..7 ----
    RYP(3, 3); RYP(2, 4); RYP(1, 5); RYP(0, 6); RYI(7);
#pragma unroll
    for (int p = 0; p < 16; ++p) v[p] *= (__popc(p) & 1) ? mA1 : mA0;
    RYP(3, 11); RYP(2, 12); RYP(1, 13); RYP(0, 14); RYI(15);

    // ---- transpose A->B ----
#pragma unroll
    for (int k = 0; k < 8; ++k)
        W[l3 * 8 + (k ^ l3)] = make_float4(v[2*k].x, v[2*k].y, v[2*k+1].x, v[2*k+1].y);
#pragma unroll
    for (int g = 0; g < 8; ++g) {
        float4 f = W[g * 8 + (l3 ^ g)];
        v[2 * g] = mk2(f.x, f.y); v[2 * g + 1] = mk2(f.z, f.w);
    }

    // ---- B: layer-1 wires 0,1,2 ; CZ1 ; layer-2 {w0,w1,w6,w7} ; CZ2 ----
    RYP(3, 8); RYP(2, 9); RYP(1, 10);
#pragma unroll
    for (int p = 0; p < 16; ++p) {           // CZ1
        const int w0 = (p >> 3) & 1, w1 = (p >> 2) & 1;
        if (w0 & w1)      v[p] = -v[p];
        else if (w0 ^ w1) v[p] *= (__popc(p & 3) & 1) ? -mBp : mBp;
    }
    RYP(3, 16); RYP(2, 17); RYP(0, 18); RYI(19);
#pragma unroll
    for (int p = 0; p < 16; ++p) {           // CZ2
        const int w0 = (p >> 3) & 1, w1 = (p >> 2) & 1;
        if (w0 & w1)      v[p] = -v[p];
        else if (w0 ^ w1) v[p] *= (__popc(p & 3) & 1) ? -mBp : mBp;
    }
#undef RYP
#undef RYI

    // ---- epilogue: observables on wires 6,7 (in-lane bits 1,0 in B) ----
    float X6 = 0, X7 = 0, XX = 0, YY = 0, Z6 = 0, Z7 = 0, ZZ = 0;
#pragma unroll
    for (int g = 0; g < 8; ++g) {
        float q0 = v[2*g].x, q1 = v[2*g].y, q2 = v[2*g+1].x, q3 = v[2*g+1].y;
        X6 += q0 * q2 + q1 * q3;
        X7 += q0 * q1 + q2 * q3;
        XX += q0 * q3 + q1 * q2;
        YY += q1 * q2 - q0 * q3;
        float s0 = q0*q0, s1 = q1*q1, s2 = q2*q2, s3 = q3*q3;
        Z6 += s0 + s1 - s2 - s3;
        Z7 += s0 - s1 + s2 - s3;
        ZZ += s0 - s1 - s2 + s3;
    }
    X6 *= 2.f; X7 *= 2.f; XX *= 2.f; YY *= 2.f;

#pragma unroll
    for (int m = 1; m < 8; m <<= 1) {
        nrm2 += __shfl_xor(nrm2, m);
        X6 += __shfl_xor(X6, m);  X7 += __shfl_xor(X7, m);
        XX += __shfl_xor(XX, m);  YY += __shfl_xor(YY, m);
        Z6 += __shfl_xor(Z6, m);  Z7 += __shfl_xor(Z7, m);
        ZZ += __shfl_xor(ZZ, m);
    }

    if (eb < batch) {
        const float inv = 1.f / nrm2;        // gates are orthogonal: norm deferred
        float* o = out + (size_t)eb * 9;
        const int t = l3;
        if (t < 7) {
            float val = (t == 0) ? X6 : (t == 1) ? Z6 : (t == 2) ? X7
                      : (t == 3) ? Z7 : (t == 4) ? XX : (t == 5) ? YY : ZZ;
            int off = t + (t >= 1 ? 1 : 0) + (t >= 3 ? 1 : 0);  // 0,2,3,5,6,7,8
            o[off] = val * inv;
        } else {
            o[1] = 0.f;                      // <Y6> == 0 exactly (real state)
            o[4] = 0.f;                      // <Y7> == 0 exactly
        }
    }
}

extern "C" void kernel_launch(void* const* d_in, const int* in_sizes, int n_in,
                              void* d_out, int out_size, void* d_ws, size_t ws_size,
                              hipStream_t stream) {
    const float* x = (const float*)d_in[0];
    const float* w = (const float*)d_in[1];
    float* out = (float*)d_out;
    const int batch = in_sizes[0] / DIM;

    const int waves  = (batch + 7) / 8;
    const int blocks = (waves + 3) / 4;      // 4 waves / 256-thread block
    qae_kernel<<<blocks, 256, 0, stream>>>(x, w, out, batch);
}

// Round 4
// 78.890 us; speedup vs baseline: 1.5061x; 1.0093x over previous
//
#include <hip/hip_runtime.h>
#include <math.h>

#define DIM 256
typedef float v2f __attribute__((ext_vector_type(2)));

__device__ __forceinline__ v2f mk2(float a, float b) { v2f r; r.x = a; r.y = b; return r; }

// wave-uniform broadcast lane->SGPR
__device__ __forceinline__ float rl(float v, int l) {
    return __uint_as_float(__builtin_amdgcn_readlane(__float_as_uint(v), l));
}

// RY on v2f-index bit B2 of an 8-entry array (amp bit B2+1).
// lo' = c*lo - s*hi ; hi' = s*lo + c*hi   (RY = [[c,-s],[s,c]])
template<int B2>
__device__ __forceinline__ void ry_pk(v2f* v, float c, float s) {
#pragma unroll
    for (int p = 0; p < 8; ++p)
        if (!(p & (1 << B2))) {
            const int q = p | (1 << B2);
            v2f lo = v[p], hi = v[q];
            v[p] = c * lo - s * hi;
            v[q] = s * lo + c * hi;
        }
}

// RY on the in-float2 amp bit
__device__ __forceinline__ void ry_intra(v2f* v, float c, float s) {
#pragma unroll
    for (int p = 0; p < 8; ++p) {
        float lo = v[p].x, hi = v[p].y;
        v[p].x = fmaf(-s, hi, c * lo);
        v[p].y = fmaf(s, lo, c * hi);
    }
}

// One wave = 4 elements (16 lanes/elem, 16 amps = 8 float2/lane).
// Canonical amp idx bits (MSB..LSB): w0 w1 w2 w3 w4 w5 w6 w7.
// Layout B': lane nib = (w2w3w4w5); in-lane v2f p: bit2=w0,bit1=w1,bit0=w6, comp=w7.
// Layout A': lane nib = (w0,w1,w6,w7)=(bit3..bit0); in-lane p: bit2=w2,bit1=w3,bit0=w4, comp=w5.
// LDS per element: 4 chunks (w0w1) * 17 float4 (16 slots + 1 pad) = 272 floats;
// B'-side = 4x float4 @ chunk jhi*68; A'-side = 16x b32, affine offsets i*4.
// Dropped exactly (commute with observables on wires 6,7): weights 18..21, 24, 25.
__global__ __launch_bounds__(256, 6) void qae_kernel(const float* __restrict__ x,
                                                     const float* __restrict__ w,
                                                     float* __restrict__ out,
                                                     int batch) {
    __shared__ float lds[4 * 4 * 272];       // 4 waves * 4 elem * 272 floats = 17408 B
    const int lane = threadIdx.x & 63;
    const int wid  = threadIdx.x >> 6;
    const int wave = blockIdx.x * 4 + wid;
    const int nib  = lane & 15;
    const int e    = lane >> 4;
    const int eb   = wave * 4 + e;
    float* WB = lds + wid * 1088 + e * 272;  // this element's LDS region
    float* pB = WB + nib * 4;                // B'-side float4 base (chunk at +68*jhi)
    float* pA = WB + (nib >> 2) * 68 + (nib & 3);  // A'-side scalar base (amp i at +i*4)

    // in-wave trig: lanes 0..19 -> weights {0..17, 22, 23}
    float h = 0.f;
    if (lane < 20) h = 0.5f * w[lane < 18 ? lane : lane + 4];
    const float cv = __cosf(h), sv = __sinf(h);
#define RYP(B2, slot) ry_pk<B2>(v, rl(cv, slot), rl(sv, slot))
#define RYI(slot)     ry_intra(v, rl(cv, slot), rl(sv, slot))

    // CZ factors. Exponent e = w0*w1 + (w0+w1)*(w2+..+w7).
    // A' (nib = w0w1w6w7): per-amp sign = f(popc(i)) with per-lane gE/gO.
    float gE, gO;
    {
        const int w0 = (nib >> 3) & 1, w1 = (nib >> 2) & 1;
        const float s0 = (__popc(nib & 3) & 1) ? -1.f : 1.f;   // (-1)^(w6+w7)
        if (w0 & w1)      { gE = -1.f; gO = -1.f; }
        else if (w0 ^ w1) { gE = s0;   gO = -s0;  }
        else              { gE = 1.f;  gO = 1.f;  }
    }
    const v2f mAe = mk2(gE, gO), mAo = mk2(gO, gE);
    // B' (nib = w2w3w4w5): pL = (-1)^popc(nib)
    const float pL = (__popc(nib) & 1) ? -1.f : 1.f;
    const v2f mBx0 = mk2(pL, -pL), mBx1 = mk2(-pL, pL);

    // load in B' (coalesced: 16 lanes x 16B = 256B per element per chunk)
    v2f v[8];
    if (eb < batch) {
        const float* xp = x + (size_t)eb * DIM + nib * 4;
#pragma unroll
        for (int u = 0; u < 4; ++u) {
            float4 f = *(const float4*)(xp + u * 64);
            v[2 * u]     = mk2(f.x, f.y);
            v[2 * u + 1] = mk2(f.z, f.w);
        }
    } else {
#pragma unroll
        for (int p = 0; p < 8; ++p) v[p] = mk2(0.f, 0.f);
    }

    // ---- B': layer-0 on wires 0,1,6,7 ----
    RYP(2, 0); RYP(1, 1); RYP(0, 6); RYI(7);

    // ---- T1: B' writes 4 b128, A' reads 16 b32 (wave-private, in-order DS) ----
#pragma unroll
    for (int u = 0; u < 4; ++u)
        *(float4*)(pB + u * 68) = make_float4(v[2*u].x, v[2*u].y, v[2*u+1].x, v[2*u+1].y);
#pragma unroll
    for (int p = 0; p < 8; ++p) {
        v[p].x = pA[p * 8];
        v[p].y = pA[p * 8 + 4];
    }

    // ---- A': layer-0 wires 2,3,4,5 ; CZ0 ; layer-1 wires 2,3,4,5 ----
    RYP(2, 2); RYP(1, 3); RYP(0, 4); RYI(5);
#pragma unroll
    for (int p = 0; p < 8; ++p) v[p] *= (__popc(p) & 1) ? mAo : mAe;
    RYP(2, 10); RYP(1, 11); RYP(0, 12); RYI(13);

    // ---- T2: A' writes 16 b32, B' reads 4 b128 ----
#pragma unroll
    for (int p = 0; p < 8; ++p) {
        pA[p * 8]     = v[p].x;
        pA[p * 8 + 4] = v[p].y;
    }
#pragma unroll
    for (int u = 0; u < 4; ++u) {
        float4 f = *(const float4*)(pB + u * 68);
        v[2 * u] = mk2(f.x, f.y); v[2 * u + 1] = mk2(f.z, f.w);
    }

    // ---- B': layer-1 wires 0,1,6,7 ; CZ1 ; layer-2 wires 0,1,6,7 ; CZ2 ----
    RYP(2, 8); RYP(1, 9); RYP(0, 14); RYI(15);
    v[2] *= mBx0; v[3] *= mBx1; v[4] *= mBx0; v[5] *= mBx1; v[6] = -v[6]; v[7] = -v[7];
    RYP(2, 16); RYP(1, 17); RYP(0, 18); RYI(19);
    v[2] *= mBx0; v[3] *= mBx1; v[4] *= mBx0; v[5] *= mBx1; v[6] = -v[6]; v[7] = -v[7];
#undef RYP
#undef RYI

    // ---- epilogue: quads over (w6,w7) per u=(w0w1); norm from state (orthogonal U) ----
    float X6 = 0, X7 = 0, XX = 0, YY = 0, Z6 = 0, Z7 = 0, ZZ = 0, N = 0;
#pragma unroll
    for (int u = 0; u < 4; ++u) {
        float q0 = v[2*u].x, q1 = v[2*u].y, q2 = v[2*u+1].x, q3 = v[2*u+1].y;
        X6 += q0 * q2 + q1 * q3;
        X7 += q0 * q1 + q2 * q3;
        XX += q0 * q3 + q1 * q2;
        YY += q1 * q2 - q0 * q3;
        float t01p = q0*q0 + q1*q1, t01m = q0*q0 - q1*q1;
        float t23p = q2*q2 + q3*q3, t23m = q2*q2 - q3*q3;
        N  += t01p + t23p;
        Z6 += t01p - t23p;
        Z7 += t01m + t23m;
        ZZ += t01m - t23m;
    }
    X6 *= 2.f; X7 *= 2.f; XX *= 2.f; YY *= 2.f;

    // butterfly over the 16 lanes of this element
#pragma unroll
    for (int m = 1; m < 16; m <<= 1) {
        N  += __shfl_xor(N, m);
        X6 += __shfl_xor(X6, m);  X7 += __shfl_xor(X7, m);
        XX += __shfl_xor(XX, m);  YY += __shfl_xor(YY, m);
        Z6 += __shfl_xor(Z6, m);  Z7 += __shfl_xor(Z7, m);
        ZZ += __shfl_xor(ZZ, m);
    }

    if (eb < batch) {
        const float inv = 1.f / N;
        float* o = out + (size_t)eb * 9;
        const int t = nib;
        if (t < 7) {
            float val = (t == 0) ? X6 : (t == 1) ? Z6 : (t == 2) ? X7
                      : (t == 3) ? Z7 : (t == 4) ? XX : (t == 5) ? YY : ZZ;
            int off = t + (t >= 1 ? 1 : 0) + (t >= 3 ? 1 : 0);  // 0,2,3,5,6,7,8
            o[off] = val * inv;
        } else if (t == 7) {
            o[1] = 0.f;                      // <Y6> == 0 exactly (real state)
            o[4] = 0.f;                      // <Y7> == 0 exactly
        }
    }
}

extern "C" void kernel_launch(void* const* d_in, const int* in_sizes, int n_in,
                              void* d_out, int out_size, void* d_ws, size_t ws_size,
                              hipStream_t stream) {
    const float* x = (const float*)d_in[0];
    const float* w = (const float*)d_in[1];
    float* out = (float*)d_out;
    const int batch = in_sizes[0] / DIM;

    const int waves  = (batch + 3) / 4;      // 4 elements per wave
    const int blocks = (waves + 3) / 4;      // 4 waves per 256-thread block
    qae_kernel<<<blocks, 256, 0, stream>>>(x, w, out, batch);
}